// Round 4
// baseline (3516.678 us; speedup 1.0000x reference)
//
#include <hip/hip_runtime.h>

// ---------------------------------------------------------------------------
// 2-layer LSTM, T=512 B=32 I=512 H=1024 — persistent kernel, layer-pipelined.
// R4: epoch-aggregated sync + gates off the barrier.
//  - WG0/wave0 polls all 512 flags (32 lines); publishes ONE epoch dword.
//    All other WGs poll 1 line. Poll traffic drops ~32x (R3's residual killer).
//  - ONE __syncthreads per step. Gate math on wave1 (L0) / wave5 (L1) runs
//    AFTER the barrier; next step's part[] overwrite is ordered by the epoch
//    (epoch>=s+1 implies all WGs' gate waves posted flags, hence finished
//    reading part[]), so pollers spin WHILE gates run everywhere (overlap).
//  - combined go condition (flag0 & flag1), flag1 seeded =1 by wave5 at s=0.
//  - out[] stores moved after the flag post (off the vmcnt drain path).
// Coherence: write-once h slots; producer h stores sc0|sc1 (ack at L3) then
// vmcnt(0) then flag (sc0|sc1). Consumers: normal cached loads (slot written
// exactly once before any read; dispatch acquire invalidates stale L2 across
// graph replays — validated R2/R3).
// ---------------------------------------------------------------------------

typedef unsigned short u16;
typedef __attribute__((ext_vector_type(8))) __bf16 bf16x8;
typedef __attribute__((ext_vector_type(8))) u16 u16x8;
typedef __attribute__((ext_vector_type(4))) float f32x4;
typedef __attribute__((ext_vector_type(2))) float f32x2;
typedef __attribute__((ext_vector_type(4))) int i32x4;
typedef __attribute__((ext_vector_type(4))) unsigned int u32x4;

#define HN_OFF 16777216   // 512*32*1024
#define CN_OFF 16842752   // HN_OFF + 2*32*1024

__device__ __forceinline__ u16 f2bf(float f) {   // RNE f32 -> bf16 (finite)
  unsigned u = __builtin_bit_cast(unsigned, f);
  u += 0x7FFFu + ((u >> 16) & 1u);
  return (u16)(u >> 16);
}
__device__ __forceinline__ float sgm(float x) { return 1.f / (1.f + __expf(-x)); }
__device__ __forceinline__ float tnh(float x) { return 2.f / (1.f + __expf(-2.f * x)) - 1.f; }

__device__ __forceinline__ bf16x8 ld16(const u16* p) {            // normal cached
  u32x4 v = *reinterpret_cast<const u32x4*>(p);
  return __builtin_bit_cast(bf16x8, v);
}
__device__ __forceinline__ bf16x8 lds16(const char* p) {
  u32x4 v = *reinterpret_cast<const u32x4*>(p);
  return __builtin_bit_cast(bf16x8, v);
}
__device__ __forceinline__ f32x4 mfma16(bf16x8 a, bf16x8 b, f32x4 c) {
  return __builtin_amdgcn_mfma_f32_16x16x32_bf16(a, b, c, 0, 0, 0);
}

// Aggregator: poll all 512 flags (flag0[256] | flag1[256], 32 lines).
__device__ __forceinline__ void poll_flags(const int* f, int lane, int s) {
  const int* p0 = f + (lane << 2);
  const int* p1 = f + 256 + (lane << 2);
  for (;;) {
    i32x4 a, b;
    asm volatile("global_load_dwordx4 %0, %2, off sc0 sc1\n\t"
                 "global_load_dwordx4 %1, %3, off sc0 sc1\n\t"
                 "s_waitcnt vmcnt(0)"
                 : "=v"(a), "=v"(b) : "v"(p0), "v"(p1) : "memory");
    if (__all((a[0] >= s) & (a[1] >= s) & (a[2] >= s) & (a[3] >= s) &
              (b[0] >= s) & (b[1] >= s) & (b[2] >= s) & (b[3] >= s))) break;
  }
}
// Consumers: poll the single epoch dword (1 line, lane-uniform -> 1 request).
__device__ __forceinline__ void poll_epoch(const int* ep, int s) {
  for (;;) {
    int e;
    asm volatile("global_load_dword %0, %1, off sc0 sc1\n\ts_waitcnt vmcnt(0)"
                 : "=v"(e) : "v"(ep) : "memory");
    if (e >= s) break;
  }
}

// Dual-B h0 chunk: one A-load pair feeds Whh0 (L0, p) AND Wxh1 (L1 x-proj, q).
template <int C0, int C1>
__device__ __forceinline__ void chunks_h0(const u16* __restrict__ A,
                                          const char* w0, const char* w1, int lane,
                                          f32x4& p0, f32x4& p1, f32x4& q0, f32x4& q1) {
  const int r = lane & 15, kq = (lane >> 4) * 8, swz = (r & 7) << 4;
#pragma unroll
  for (int c = C0; c < C1; ++c) {
    const u16* ap = A + r * 1024 + c * 32 + kq;
    bf16x8 a0 = ld16(ap);
    bf16x8 a1 = ld16(ap + 16 * 1024);
    bf16x8 b0 = lds16(w0 + r * 3072 + ((c * 64 + kq * 2) ^ swz));
    bf16x8 b1 = lds16(w1 + r * 4096 + (((c + 32) * 64 + kq * 2) ^ swz));
    p0 = mfma16(a0, b0, p0);  p1 = mfma16(a1, b0, p1);
    q0 = mfma16(a0, b1, q0);  q1 = mfma16(a1, b1, q1);
  }
}
template <int C0, int C1>
__device__ __forceinline__ void chunks_h1(const u16* __restrict__ A,
                                          const char* w1, int lane,
                                          f32x4& p0, f32x4& p1) {
  const int r = lane & 15, kq = (lane >> 4) * 8, swz = (r & 7) << 4;
#pragma unroll
  for (int c = C0; c < C1; ++c) {
    const u16* ap = A + r * 1024 + c * 32 + kq;
    bf16x8 a0 = ld16(ap);
    bf16x8 a1 = ld16(ap + 16 * 1024);
    bf16x8 bw = lds16(w1 + r * 4096 + ((c * 64 + kq * 2) ^ swz));
    p0 = mfma16(a0, bw, p0);  p1 = mfma16(a1, bw, p1);
  }
}
template <int C0, int C1>
__device__ __forceinline__ void chunks_x(const u16* __restrict__ A,
                                         const char* w0, int lane,
                                         f32x4& q0, f32x4& q1) {
  const int r = lane & 15, kq = (lane >> 4) * 8, swz = (r & 7) << 4;
#pragma unroll
  for (int c = C0; c < C1; ++c) {
    const u16* ap = A + r * 512 + c * 32 + kq;
    bf16x8 a0 = ld16(ap);
    bf16x8 a1 = ld16(ap + 16 * 512);
    bf16x8 bw = lds16(w0 + r * 3072 + (((c + 32) * 64 + kq * 2) ^ swz));
    q0 = mfma16(a0, bw, q0);  q1 = mfma16(a1, bw, q1);
  }
}

// LDS (dynamic, 151744 B):
//   [0,      49152)  w0: 16 rows x 1536 bf16 [Whh0|Wxh0], XOR-swizzled
//   [49152, 114688)  w1: 16 rows x 2048 bf16 [Whh1|Wxh1], XOR-swizzled
//   [114688,151552)  part[16][32][18] f32 (0-3 L0h0, 4-7 L1h1, 8-11 L1xg, 12-15 L0x)
//   [151552]bias0[16]  [151616]bias1[16]  [151680] go
__global__ __launch_bounds__(512, 2) void lstm_fused(
    const u16* __restrict__ xbf,
    const float* __restrict__ Whh0, const float* __restrict__ Wxh0,
    const float* __restrict__ Whh1, const float* __restrict__ Wxh1,
    const float* __restrict__ bxh0, const float* __restrict__ bhh0,
    const float* __restrict__ bxh1, const float* __restrict__ bhh1,
    u16* __restrict__ h0seq, u16* __restrict__ h1seq,
    int* __restrict__ flagbase,   // flag0[256] | flag1[256] | epoch (line 32)
    float* __restrict__ out) {
  extern __shared__ char smem[];
  const char* w0 = smem;
  const char* w1 = smem + 49152;
  auto part = reinterpret_cast<float(*)[32][18]>(smem + 114688);
  float* bias0 = reinterpret_cast<float*>(smem + 151552);
  float* bias1 = reinterpret_cast<float*>(smem + 151616);
  volatile int* go = reinterpret_cast<volatile int*>(smem + 151680);

  int* flag0 = flagbase;
  int* flag1 = flagbase + 256;
  int* epoch = flagbase + 512;

  const int tid = threadIdx.x;
  const int wg = blockIdx.x;
  const int wid = tid >> 6, lane = tid & 63;

  if (tid == 0) go[0] = 0;
  // ---- LDS weight fill, f32 -> bf16 inline (row n -> global gate*1024+wg*4+jj)
  for (int g = tid; g < 3072; g += 512) {
    int n = g / 192, gi = g % 192, kc = gi * 8;
    int gr = ((n >> 2) << 10) + (wg << 2) + (n & 3);
    const float* src = (kc < 1024) ? (Whh0 + gr * 1024 + kc) : (Wxh0 + gr * 512 + (kc - 1024));
    f32x4 lo = *reinterpret_cast<const f32x4*>(src);
    f32x4 hi = *reinterpret_cast<const f32x4*>(src + 4);
    u16x8 o;
    o[0]=f2bf(lo[0]); o[1]=f2bf(lo[1]); o[2]=f2bf(lo[2]); o[3]=f2bf(lo[3]);
    o[4]=f2bf(hi[0]); o[5]=f2bf(hi[1]); o[6]=f2bf(hi[2]); o[7]=f2bf(hi[3]);
    *reinterpret_cast<u16x8*>(smem + n * 3072 + ((gi * 16) ^ ((n & 7) << 4))) = o;
  }
  for (int g = tid; g < 4096; g += 512) {
    int n = g / 256, gi = g % 256, kc = gi * 8;
    int gr = ((n >> 2) << 10) + (wg << 2) + (n & 3);
    const float* src = (kc < 1024) ? (Whh1 + gr * 1024 + kc) : (Wxh1 + gr * 1024 + (kc - 1024));
    f32x4 lo = *reinterpret_cast<const f32x4*>(src);
    f32x4 hi = *reinterpret_cast<const f32x4*>(src + 4);
    u16x8 o;
    o[0]=f2bf(lo[0]); o[1]=f2bf(lo[1]); o[2]=f2bf(lo[2]); o[3]=f2bf(lo[3]);
    o[4]=f2bf(hi[0]); o[5]=f2bf(hi[1]); o[6]=f2bf(hi[2]); o[7]=f2bf(hi[3]);
    *reinterpret_cast<u16x8*>(smem + 49152 + n * 4096 + ((gi * 16) ^ ((n & 7) << 4))) = o;
  }
  if (tid < 16) {
    int gr = ((tid >> 2) << 10) + (wg << 2) + (tid & 3);
    bias0[tid] = bxh0[gr] + bhh0[gr];
    bias1[tid] = bxh1[gr] + bhh1[gr];
  }
  __syncthreads();

  float c0a = 0.f, c0b = 0.f, c1a = 0.f, c1b = 0.f;   // cell state (wave1/wave5)
  const int bg = lane >> 1, jjb = (lane & 1) << 1;    // gate-math mapping
  const int colb = (wg << 2) + jjb;

  for (int s = 0; s <= 512; ++s) {
    const u16* h0slot = h0seq + s * 32768;          // h0 output of t=s-1 (slot0 zeros)
    const u16* h1prev = h1seq + (s - 1) * 32768;    // h1 output of t=s-2
    f32x4 p0 = {0,0,0,0}, p1 = {0,0,0,0}, q0 = {0,0,0,0}, q1 = {0,0,0,0};

    // ---- pre-dependency: L0 x-projection (waves 4-7; pure x, no flag dep)
    if (wid >= 4 && s < 512) {
      const u16* xbt = xbf + s * 16384;
      if      (wid == 4) chunks_x<0,  4 >(xbt, w0, lane, q0, q1);
      else if (wid == 5) chunks_x<4,  8 >(xbt, w0, lane, q0, q1);
      else if (wid == 6) chunks_x<8,  12>(xbt, w0, lane, q0, q1);
      else               chunks_x<12, 16>(xbt, w0, lane, q0, q1);
    }

    // ---- dependency: epoch >= s (combined flag0 & flag1 condition)
    if (s >= 1) {
      if (wid == 0) {
        if (wg == 0) {
          poll_flags(flag0, lane, s);
          if (lane == 0) {
            int sv = s;
            asm volatile("global_store_dword %0, %1, off sc0 sc1"
                         :: "v"(epoch), "v"(sv) : "memory");
          }
        } else {
          poll_epoch(epoch, s);
        }
        if (lane == 0) go[0] = s;
      } else {
        while (go[0] < s) __builtin_amdgcn_s_sleep(1);
      }
    }

    // ---- h-dependent chunks
    if (wid < 4) {
      if      (wid == 0) chunks_h0<0,  8 >(h0slot, w0, w1, lane, p0, p1, q0, q1);
      else if (wid == 1) chunks_h0<8,  16>(h0slot, w0, w1, lane, p0, p1, q0, q1);
      else if (wid == 2) chunks_h0<16, 24>(h0slot, w0, w1, lane, p0, p1, q0, q1);
      else               chunks_h0<24, 32>(h0slot, w0, w1, lane, p0, p1, q0, q1);
    } else if (s >= 1) {
      if      (wid == 4) chunks_h1<0,  8 >(h1prev, w1, lane, p0, p1);
      else if (wid == 5) chunks_h1<8,  16>(h1prev, w1, lane, p0, p1);
      else if (wid == 6) chunks_h1<16, 24>(h1prev, w1, lane, p0, p1);
      else               chunks_h1<24, 32>(h1prev, w1, lane, p0, p1);
    }

    {   // ---- partial-sum write (D-frag: col=lane&15, row=(lane>>4)*4+j)
      const int n = lane & 15, br = (lane >> 4) * 4;
#pragma unroll
      for (int j = 0; j < 4; ++j) {
        part[wid][br + j][n]          = p0[j];
        part[wid][br + j + 16][n]     = p1[j];
        part[8 + wid][br + j][n]      = q0[j];
        part[8 + wid][br + j + 16][n] = q1[j];
      }
    }
    __syncthreads();     // the ONLY barrier per step

    if (wid == 1) {                  // ---- L0 gates (t0 = s), after barrier
      if (s < 512) {
        float v[4][2];
#pragma unroll
        for (int gi = 0; gi < 4; ++gi) {
          const int n = (gi << 2) + jjb;
          float s0 = bias0[n], s1 = bias0[n + 1];
#pragma unroll
          for (int p = 0; p < 4; ++p) {
            f32x2 a = *reinterpret_cast<const f32x2*>(&part[p][bg][n]);
            f32x2 b = *reinterpret_cast<const f32x2*>(&part[12 + p][bg][n]);
            s0 += a[0] + b[0];  s1 += a[1] + b[1];
          }
          v[gi][0] = s0; v[gi][1] = s1;
        }
        c0a = sgm(v[1][0]) * c0a + sgm(v[0][0]) * tnh(v[2][0]);
        c0b = sgm(v[1][1]) * c0b + sgm(v[0][1]) * tnh(v[2][1]);
        const float ha = sgm(v[3][0]) * tnh(c0a), hb = sgm(v[3][1]) * tnh(c0b);
        unsigned pk = (unsigned)f2bf(ha) | ((unsigned)f2bf(hb) << 16);
        u16* hp = h0seq + (s + 1) * 32768 + bg * 1024 + colb;
        asm volatile("global_store_dword %0, %1, off sc0 sc1" :: "v"(hp), "v"(pk) : "memory");
        asm volatile("s_waitcnt vmcnt(0)" ::: "memory");   // h at L3 before flag
        if (lane == 0) {
          int* fp = flag0 + wg;  int fv = s + 1;
          asm volatile("global_store_dword %0, %1, off sc0 sc1" :: "v"(fp), "v"(fv) : "memory");
        }
        if (s == 511) {              // off the drain path
          *reinterpret_cast<f32x2*>(out + HN_OFF + bg * 1024 + colb) = f32x2{ha, hb};
          *reinterpret_cast<f32x2*>(out + CN_OFF + bg * 1024 + colb) = f32x2{c0a, c0b};
        }
      }
    } else if (wid == 5) {           // ---- L1 gates (t1 = s-1), after barrier
      if (s >= 1) {
        float v[4][2];
#pragma unroll
        for (int gi = 0; gi < 4; ++gi) {
          const int n = (gi << 2) + jjb;
          float s0 = bias1[n], s1 = bias1[n + 1];
#pragma unroll
          for (int p = 4; p < 12; ++p) {
            f32x2 a = *reinterpret_cast<const f32x2*>(&part[p][bg][n]);
            s0 += a[0];  s1 += a[1];
          }
          v[gi][0] = s0; v[gi][1] = s1;
        }
        c1a = sgm(v[1][0]) * c1a + sgm(v[0][0]) * tnh(v[2][0]);
        c1b = sgm(v[1][1]) * c1b + sgm(v[0][1]) * tnh(v[2][1]);
        const float ha = sgm(v[3][0]) * tnh(c1a), hb = sgm(v[3][1]) * tnh(c1b);
        unsigned pk = (unsigned)f2bf(ha) | ((unsigned)f2bf(hb) << 16);
        u16* hp = h1seq + s * 32768 + bg * 1024 + colb;
        asm volatile("global_store_dword %0, %1, off sc0 sc1" :: "v"(hp), "v"(pk) : "memory");
        asm volatile("s_waitcnt vmcnt(0)" ::: "memory");
        if (lane == 0) {
          int* fp = flag1 + wg;  int fv = s + 1;
          asm volatile("global_store_dword %0, %1, off sc0 sc1" :: "v"(fp), "v"(fv) : "memory");
        }
        const int t1 = s - 1;        // out[] off the drain path
        *reinterpret_cast<f32x2*>(out + t1 * 32768 + bg * 1024 + colb) = f32x2{ha, hb};
        if (t1 == 511) {
          *reinterpret_cast<f32x2*>(out + HN_OFF + 32768 + bg * 1024 + colb) = f32x2{ha, hb};
          *reinterpret_cast<f32x2*>(out + CN_OFF + 32768 + bg * 1024 + colb) = f32x2{c1a, c1b};
        }
      } else if (lane == 0) {        // s == 0: seed flag1 = 1 (h1 slot0 = memset zeros)
        int* fp = flag1 + wg;  int fv = 1;
        asm volatile("global_store_dword %0, %1, off sc0 sc1" :: "v"(fp), "v"(fv) : "memory");
      }
    }
  }
}

__global__ void cvt_bf16(const float* __restrict__ s, u16* __restrict__ d, int n) {
  int i = (blockIdx.x * blockDim.x + threadIdx.x) * 4;
  const int stride = gridDim.x * blockDim.x * 4;
  typedef __attribute__((ext_vector_type(4))) u16 u16x4;
  for (; i < n; i += stride) {
    f32x4 v = *reinterpret_cast<const f32x4*>(s + i);
    u16x4 o;
    o[0] = f2bf(v[0]); o[1] = f2bf(v[1]); o[2] = f2bf(v[2]); o[3] = f2bf(v[3]);
    *reinterpret_cast<u16x4*>(d + i) = o;
  }
}

// ws (bytes): xbf [0,16M) | h0seq [16777216,+513*65536) | h1seq [50397184,+same)
//             | flagbase [84017152, +4096): flag0[256] | flag1[256] | epoch
extern "C" void kernel_launch(void* const* d_in, const int* in_sizes, int n_in,
                              void* d_out, int out_size, void* d_ws, size_t ws_size,
                              hipStream_t stream) {
  const float* x    = (const float*)d_in[0];
  const float* Wxh0 = (const float*)d_in[1];
  const float* bxh0 = (const float*)d_in[2];
  const float* Whh0 = (const float*)d_in[3];
  const float* bhh0 = (const float*)d_in[4];
  const float* Wxh1 = (const float*)d_in[5];
  const float* bxh1 = (const float*)d_in[6];
  const float* Whh1 = (const float*)d_in[7];
  const float* bhh1 = (const float*)d_in[8];
  char* ws = (char*)d_ws;
  u16* xbf      = (u16*)(ws);
  u16* h0seq    = (u16*)(ws + 16777216);
  u16* h1seq    = (u16*)(ws + 50397184);
  int* flagbase = (int*)(ws + 84017152);

  cvt_bf16<<<2048, 256, 0, stream>>>(x, xbf, 512 * 32 * 512);
  (void)hipMemsetAsync(h0seq, 0, 65536, stream);     // h0 slot 0 = zeros
  (void)hipMemsetAsync(h1seq, 0, 65536, stream);     // h1 slot 0 = zeros
  (void)hipMemsetAsync(flagbase, 0, 4096, stream);   // flags + epoch

  (void)hipFuncSetAttribute(reinterpret_cast<const void*>(lstm_fused),
                            hipFuncAttributeMaxDynamicSharedMemorySize, 151744);
  lstm_fused<<<dim3(256), dim3(512), 151744, stream>>>(
      xbf, Whh0, Wxh0, Whh1, Wxh1, bxh0, bhh0, bxh1, bhh1,
      h0seq, h1seq, flagbase, (float*)d_out);
}